// Round 17
// baseline (178.562 us; speedup 1.0000x reference)
//
#include <hip/hip_runtime.h>

typedef unsigned int uint;
typedef unsigned short u16;
typedef _Float16 f16;
typedef __attribute__((ext_vector_type(8))) _Float16 f16x8;
typedef __attribute__((ext_vector_type(4))) float f32x4;

#define NGR 512
#define EDG 1048576

union uhcv { u16 u; f16 h; };
__device__ __forceinline__ u16 f2h(float f) { uhcv x; x.h = (f16)f; return x.u; }
__device__ __forceinline__ float h2f(u16 v) { uhcv x; x.u = v; return (float)x.h; }

// ---------------- fragment-pack weights f32 -> f16 ----------------
// W1p  layout [kk(7)][ks(4)][nt(16)][G(4)][l15(16)][8]  : frag (k,ks,ntile) is 1024 contiguous bytes
// W23p layout [kk(7)][ks(8)][nt(8)] [G(4)][l15(16)][8]
__global__ __launch_bounds__(256) void k_prep(const float* __restrict__ W1, const float* __restrict__ W2,
                                              const float* __restrict__ W3,
                                              u16* __restrict__ W1p, u16* __restrict__ W23p) {
  int b = blockIdx.x, t = threadIdx.x;
  if (b < 112) {                    // W1p: 28672 groups of 8
    int g = b * 256 + t;
    int l15 = g & 15, G = (g >> 4) & 3, nt = (g >> 6) & 15, ksk = g >> 10;  // ksk = kk*4+ks
    int f0 = ksk * 32 + G * 8;      // = kk*128 + ks*32 + G*8
    int n = nt * 16 + l15;
    u16 out[8];
    #pragma unroll
    for (int j = 0; j < 8; ++j) out[j] = f2h(W1[(size_t)(f0 + j) * 256 + n]);
    *(uint4*)&W1p[(size_t)g * 8] = *(uint4*)out;
  } else {                          // W23p: 28672 groups
    int g = (b - 112) * 256 + t;
    int l15 = g & 15, G = (g >> 4) & 3, nt = (g >> 6) & 7, ksk = g >> 9;    // ksk = kk*8+ks
    int f0 = ksk * 32 + G * 8;      // = kk*256 + ks*32 + G*8
    int n = nt * 16 + l15;
    u16 out[8];
    #pragma unroll
    for (int j = 0; j < 8; ++j) {
      int f = f0 + j;
      float v = (n < 64) ? W2[(size_t)f * 64 + n] : W3[(size_t)f * 64 + (n - 64)];
      out[j] = f2h(v);
    }
    *(uint4*)&W23p[(size_t)g * 8] = *(uint4*)out;
  }
}

// ---------------- coalesced tiled transpose f32 -> f16 (head weight only) ----------------
template<int R, int C>
__global__ __launch_bounds__(256) void k_tr(const float* __restrict__ A, u16* __restrict__ dst) {
  __shared__ u16 tile[64][68];
  int r0 = blockIdx.x * 64, c0 = blockIdx.y * 64;
  int t = threadIdx.x;
  int cl = t & 63, rl = t >> 6;
  #pragma unroll
  for (int pass = 0; pass < 16; ++pass) {
    int r = r0 + rl + pass * 4, c = c0 + cl;
    float v = 0.f;
    if (r < R && c < C) v = A[(size_t)r * C + c];
    tile[cl][rl + pass * 4] = f2h(v);
  }
  __syncthreads();
  int nl = t >> 2, rs = (t & 3) * 16;
  #pragma unroll
  for (int j = 0; j < 4; ++j) {
    uint2 v = *(const uint2*)&tile[nl][rs + j * 4];
    *(uint2*)&dst[(size_t)(c0 + nl) * R + r0 + rs + j * 4] = v;
  }
}

// ---------------- per-graph dense 2*Lhat (f16, [512][64][64]) ----------------
__global__ __launch_bounds__(256) void k_buildA(const int* __restrict__ ei, u16* __restrict__ Ah2) {
  int g = blockIdx.x, t = threadIdx.x;
  __shared__ float sA[64 * 66];
  __shared__ int ideg[64];
  __shared__ float sdis[64];
  for (int e = t; e < 64 * 66; e += 256) sA[e] = 0.f;
  if (t < 64) ideg[t] = 0;
  __syncthreads();
  int sl[4], dl[4];
  #pragma unroll
  for (int u = 0; u < 4; ++u) {
    int idx = g * 1024 + t + u * 256;
    sl[u] = ei[idx] & 63; dl[u] = ei[EDG + idx] & 63;
    atomicAdd(&ideg[sl[u]], 1); atomicAdd(&ideg[dl[u]], 1);
  }
  __syncthreads();
  if (t < 64) sdis[t] = rsqrtf((float)ideg[t]);
  __syncthreads();
  #pragma unroll
  for (int u = 0; u < 4; ++u) {
    float wg = -sdis[sl[u]] * sdis[dl[u]];
    atomicAdd(&sA[sl[u] * 66 + dl[u]], wg);
    atomicAdd(&sA[dl[u] * 66 + sl[u]], wg);
  }
  __syncthreads();
  for (int e = t; e < 4096; e += 256)
    Ah2[(size_t)g * 4096 + e] = f2h(2.f * sA[(e >> 6) * 66 + (e & 63)]);
}

// ======== fused main: both Cheb stages per graph, h1 stays in LDS; pool+reparam+MLP1 tail ========
// LDS: Ah[64][72] @0 | cur[64][264] @9216 (node-major) | curT[256][72] @43008 (feat-major)
//      smu2[256] @79872 (1KB) | sz[64] @80896 | total 81152 -> 2 blocks/CU
__global__ __launch_bounds__(512, 4) void k_main(
    const u16* __restrict__ Ah2, const float* __restrict__ x,
    const u16* __restrict__ W1p, const float* __restrict__ b1,
    const u16* __restrict__ W23p, const float* __restrict__ b2, const float* __restrict__ b3,
    const float* __restrict__ eps, const float* __restrict__ Wf1, const float* __restrict__ bf1,
    float* __restrict__ dout, u16* __restrict__ hh) {
  extern __shared__ char smem[];
  u16* Ah     = (u16*)(smem);
  u16* cur    = (u16*)(smem + 9216);
  u16* curT   = (u16*)(smem + 43008);
  float* smu2 = (float*)(smem + 79872);
  float* sz   = (float*)(smem + 80896);
  int g = blockIdx.x, t = threadIdx.x;
  int lane = t & 63, w = t >> 6, l15 = lane & 15, G = lane >> 4;
  int G16l = G * 16 + l15;                     // fragment lane slot (0..63)
  int mg = w >> 2, ng = w & 3;                 // phase-2 consumption split: 2 m-groups x 4 n-groups

  // stage 2*Lhat (512 uint4 = one pass of 512 threads) and T0 = x (128 feats)
  {
    const uint4* src = (const uint4*)(Ah2 + (size_t)g * 4096);
    {
      int p = t;
      int r = p >> 3, c8 = (p & 7) * 8;
      *(uint4*)&Ah[r * 72 + c8] = src[p];
    }
    const float4* xg = (const float4*)(x + (size_t)g * 8192);
    #pragma unroll
    for (int i = 0; i < 4; ++i) {
      int p = t + i * 512;
      int r = p >> 5, c4 = (p & 31) * 4;
      float4 v = xg[p];
      u16 e0 = f2h(v.x), e1 = f2h(v.y), e2 = f2h(v.z), e3 = f2h(v.w);
      uint2 pk; u16* ps = (u16*)&pk; ps[0] = e0; ps[1] = e1; ps[2] = e2; ps[3] = e3;
      *(uint2*)&cur[r * 264 + c4] = pk;
      curT[(c4 + 0) * 72 + r] = e0; curT[(c4 + 1) * 72 + r] = e1;
      curT[(c4 + 2) * 72 + r] = e2; curT[(c4 + 3) * 72 + r] = e3;
    }
  }
  __syncthreads();

  // hoist the 8 invariant Lhat fragments into registers (Ah is read-only from here on)
  f16x8 aF[2][4];
  #pragma unroll
  for (int ks = 0; ks < 2; ++ks)
    #pragma unroll
    for (int m = 0; m < 4; ++m)
      aF[ks][m] = *(const f16x8*)&Ah[(m * 16 + l15) * 72 + ks * 32 + G * 8];

  // ===== phase 1: h1 = relu(sum_k T_k @ W1[k] + b1) =====
  f32x4 accA[4][2];
  #pragma unroll
  for (int m = 0; m < 4; ++m) { accA[m][0] = (f32x4){0,0,0,0}; accA[m][1] = (f32x4){0,0,0,0}; }
  uint2 pA[4], pB[4];
  #pragma unroll
  for (int m = 0; m < 4; ++m) {
    pA[m] = *(const uint2*)&curT[(w * 16 + l15) * 72 + m * 16 + G * 4];
    pB[m] = pA[m];
  }

  for (int k = 1; k <= 7; ++k) {
    // consume T_{k-1} with W1[k-1]: fragment-packed, fully-coalesced 1KB wave loads
    #pragma unroll
    for (int ks = 0; ks < 4; ++ks) {
      f16x8 bb0 = *(const f16x8*)(W1p + (size_t)((((k - 1) * 4 + ks) * 16 + (w * 2 + 0)) * 64 + G16l) * 8);
      f16x8 bb1 = *(const f16x8*)(W1p + (size_t)((((k - 1) * 4 + ks) * 16 + (w * 2 + 1)) * 64 + G16l) * 8);
      #pragma unroll
      for (int m = 0; m < 4; ++m) {
        f16x8 a4 = *(const f16x8*)&cur[(m * 16 + l15) * 264 + ks * 32 + G * 8];
        accA[m][0] = __builtin_amdgcn_mfma_f32_16x16x32_f16(a4, bb0, accA[m][0], 0, 0, 0);
        accA[m][1] = __builtin_amdgcn_mfma_f32_16x16x32_f16(a4, bb1, accA[m][1], 0, 0, 0);
      }
    }
    if (k == 7) break;
    // T_k = (2L)@T_{k-1} - T_{k-2}: seed acc with -T_{k-2}; k==1 -> seed 0, scale 0.5
    f32x4 accY[4];
    #pragma unroll
    for (int m = 0; m < 4; ++m) {
      const u16* pp = (const u16*)&pB[m];
      #pragma unroll
      for (int r = 0; r < 4; ++r) accY[m][r] = (k >= 2) ? -h2f(pp[r]) : 0.f;
    }
    #pragma unroll
    for (int ks = 0; ks < 2; ++ks) {
      f16x8 bq = *(const f16x8*)&curT[(w * 16 + l15) * 72 + ks * 32 + G * 8];
      #pragma unroll
      for (int m = 0; m < 4; ++m)
        accY[m] = __builtin_amdgcn_mfma_f32_16x16x32_f16(aF[ks][m], bq, accY[m], 0, 0, 0);
    }
    __syncthreads();
    {
      int f = w * 16 + l15;
      float sc = (k == 1) ? 0.5f : 1.f;
      #pragma unroll
      for (int m = 0; m < 4; ++m) {
        int i0 = m * 16 + G * 4;
        uint2 pk; u16* ps = (u16*)&pk;
        #pragma unroll
        for (int r = 0; r < 4; ++r) ps[r] = f2h(sc * accY[m][r]);
        *(uint2*)&curT[f * 72 + i0] = pk;
        cur[(i0 + 0) * 264 + f] = ps[0]; cur[(i0 + 1) * 264 + f] = ps[1];
        cur[(i0 + 2) * 264 + f] = ps[2]; cur[(i0 + 3) * 264 + f] = ps[3];
        pB[m] = pA[m]; pA[m] = pk;
      }
    }
    __syncthreads();
  }
  __syncthreads();   // cons(T6) reads complete before h1 overwrites LDS

  // h1 epilogue -> phase-2 T0 (LDS + packed frags; phase-2 recurrence ownership == phase-1 output cols)
  uint2 pA2[4][2], pB2[4][2];
  #pragma unroll
  for (int nc = 0; nc < 2; ++nc) {
    int gc = w * 32 + nc * 16 + l15;
    float bias = b1[gc];
    #pragma unroll
    for (int m = 0; m < 4; ++m) {
      int i0 = m * 16 + G * 4;
      uint2 pk; u16* ps = (u16*)&pk;
      #pragma unroll
      for (int r = 0; r < 4; ++r) {
        float v = accA[m][nc][r] + bias;
        ps[r] = f2h(v > 0.f ? v : 0.f);
      }
      *(uint2*)&curT[gc * 72 + i0] = pk;
      cur[(i0 + 0) * 264 + gc] = ps[0]; cur[(i0 + 1) * 264 + gc] = ps[1];
      cur[(i0 + 2) * 264 + gc] = ps[2]; cur[(i0 + 3) * 264 + gc] = ps[3];
      pA2[m][nc] = pk; pB2[m][nc] = pk;
    }
  }
  __syncthreads();

  // ===== phase 2: out2 = sum_k T_k @ [W2|W3][k], T over h1 (256 feats) =====
  // consumption m-split: wave (mg,ng) owns m-tiles {mg*2, mg*2+1} x col-tiles {ng*2, ng*2+1}
  f32x4 accB[2][2];
  #pragma unroll
  for (int mm = 0; mm < 2; ++mm) { accB[mm][0] = (f32x4){0,0,0,0}; accB[mm][1] = (f32x4){0,0,0,0}; }
  for (int k = 1; k <= 7; ++k) {
    #pragma unroll
    for (int ks = 0; ks < 8; ++ks) {
      f16x8 bb0 = *(const f16x8*)(W23p + (size_t)((((k - 1) * 8 + ks) * 8 + (ng * 2 + 0)) * 64 + G16l) * 8);
      f16x8 bb1 = *(const f16x8*)(W23p + (size_t)((((k - 1) * 8 + ks) * 8 + (ng * 2 + 1)) * 64 + G16l) * 8);
      #pragma unroll
      for (int mm = 0; mm < 2; ++mm) {
        f16x8 a4 = *(const f16x8*)&cur[((mg * 2 + mm) * 16 + l15) * 264 + ks * 32 + G * 8];
        accB[mm][0] = __builtin_amdgcn_mfma_f32_16x16x32_f16(a4, bb0, accB[mm][0], 0, 0, 0);
        accB[mm][1] = __builtin_amdgcn_mfma_f32_16x16x32_f16(a4, bb1, accB[mm][1], 0, 0, 0);
      }
    }
    if (k == 7) break;
    f32x4 accY[4][2];
    #pragma unroll
    for (int m = 0; m < 4; ++m)
      #pragma unroll
      for (int nt = 0; nt < 2; ++nt) {
        const u16* pp = (const u16*)&pB2[m][nt];
        #pragma unroll
        for (int r = 0; r < 4; ++r) accY[m][nt][r] = (k >= 2) ? -h2f(pp[r]) : 0.f;
      }
    #pragma unroll
    for (int ks = 0; ks < 2; ++ks) {
      f16x8 bq0 = *(const f16x8*)&curT[(w * 32 + l15) * 72 + ks * 32 + G * 8];
      f16x8 bq1 = *(const f16x8*)&curT[(w * 32 + 16 + l15) * 72 + ks * 32 + G * 8];
      #pragma unroll
      for (int m = 0; m < 4; ++m) {
        accY[m][0] = __builtin_amdgcn_mfma_f32_16x16x32_f16(aF[ks][m], bq0, accY[m][0], 0, 0, 0);
        accY[m][1] = __builtin_amdgcn_mfma_f32_16x16x32_f16(aF[ks][m], bq1, accY[m][1], 0, 0, 0);
      }
    }
    __syncthreads();
    {
      float sc = (k == 1) ? 0.5f : 1.f;
      #pragma unroll
      for (int nt = 0; nt < 2; ++nt) {
        int f = w * 32 + nt * 16 + l15;
        #pragma unroll
        for (int m = 0; m < 4; ++m) {
          int i0 = m * 16 + G * 4;
          uint2 pk; u16* ps = (u16*)&pk;
          #pragma unroll
          for (int r = 0; r < 4; ++r) ps[r] = f2h(sc * accY[m][nt][r]);
          *(uint2*)&curT[f * 72 + i0] = pk;
          cur[(i0 + 0) * 264 + f] = ps[0]; cur[(i0 + 1) * 264 + f] = ps[1];
          cur[(i0 + 2) * 264 + f] = ps[2]; cur[(i0 + 3) * 264 + f] = ps[3];
          pB2[m][nt] = pA2[m][nt]; pA2[m][nt] = pk;
        }
      }
    }
    __syncthreads();
  }
  // ---- pool over 64 nodes (2-partial: mg halves) + reparameterize + MLP1 ----
  #pragma unroll
  for (int nc = 0; nc < 2; ++nc) {
    float s = 0.f;
    #pragma unroll
    for (int mm = 0; mm < 2; ++mm)
      #pragma unroll
      for (int r = 0; r < 4; ++r) s += accB[mm][nc][r];
    s += __shfl_xor(s, 16);
    s += __shfl_xor(s, 32);
    if (G == 0) smu2[mg * 128 + ng * 32 + nc * 16 + l15] = s;
  }
  __syncthreads();
  if (t < 64) {
    float m = (smu2[t] + smu2[128 + t]) * (1.f / 64.f) + b2[t];
    float l = (smu2[64 + t] + smu2[192 + t]) * (1.f / 64.f) + b3[t];
    float z = m + eps[g * 64 + t] * expf(0.5f * l);
    dout[1032192 + g * 64 + t] = m;
    dout[1032192 + 32768 + g * 64 + t] = l;
    sz[t] = z;
  }
  __syncthreads();
  if (t < 256) {
    float aq = bf1[t];
    #pragma unroll 8
    for (int j = 0; j < 64; ++j) aq += sz[j] * Wf1[j * 256 + t];
    hh[(size_t)g * 256 + t] = f2h(aq > 0.f ? aq : 0.f);
  }
}

// ---------------- sigmoid GEMM: adj = sigmoid(hh[512][256] @ Wf2t^T + bf2) ----------------
__global__ __launch_bounds__(256) void k_gemm_sig(const u16* __restrict__ A,
                                                  const u16* __restrict__ Bt,
                                                  const float* __restrict__ bias_a,
                                                  float* __restrict__ Cf32) {
  __shared__ __align__(16) u16 As[2][128 * 40];
  __shared__ __align__(16) u16 Bs[2][128 * 40];
  int t = threadIdx.x;
  int lane = t & 63, wave = t >> 6;
  int wr = wave >> 1, wc = wave & 1;
  int bm = blockIdx.x * 128, bn = blockIdx.y * 128;
  int ra = t >> 1, ka = (t & 1) * 16;
  const u16* Ap = A + (size_t)(bm + ra) * 256 + ka;
  const u16* Bp = Bt + (size_t)(bn + ra) * 256 + ka;

  f32x4 acc[4][4];
  #pragma unroll
  for (int m = 0; m < 4; ++m)
    #pragma unroll
    for (int n = 0; n < 4; ++n) acc[m][n] = (f32x4){0.f, 0.f, 0.f, 0.f};

  {
    uint4 a0 = *(const uint4*)(Ap), a1 = *(const uint4*)(Ap + 8);
    uint4 b0 = *(const uint4*)(Bp), b1 = *(const uint4*)(Bp + 8);
    *(uint4*)&As[0][ra * 40 + ka] = a0; *(uint4*)&As[0][ra * 40 + ka + 8] = a1;
    *(uint4*)&Bs[0][ra * 40 + ka] = b0; *(uint4*)&Bs[0][ra * 40 + ka + 8] = b1;
  }
  for (int ks = 0; ks < 8; ++ks) {
    int cu = ks & 1;
    uint4 na0, na1, nb0, nb1;
    bool pf = (ks + 1 < 8);
    if (pf) {
      int k0 = (ks + 1) << 5;
      na0 = *(const uint4*)(Ap + k0); na1 = *(const uint4*)(Ap + k0 + 8);
      nb0 = *(const uint4*)(Bp + k0); nb1 = *(const uint4*)(Bp + k0 + 8);
    }
    __syncthreads();
    f16x8 af[4], bfr[4];
    #pragma unroll
    for (int m = 0; m < 4; ++m)
      af[m] = *(const f16x8*)&As[cu][(wr * 64 + m * 16 + (lane & 15)) * 40 + (lane >> 4) * 8];
    #pragma unroll
    for (int n = 0; n < 4; ++n)
      bfr[n] = *(const f16x8*)&Bs[cu][(wc * 64 + n * 16 + (lane & 15)) * 40 + (lane >> 4) * 8];
    #pragma unroll
    for (int m = 0; m < 4; ++m)
      #pragma unroll
      for (int n = 0; n < 4; ++n)
        acc[m][n] = __builtin_amdgcn_mfma_f32_16x16x32_f16(af[m], bfr[n], acc[m][n], 0, 0, 0);
    if (pf) {
      int nb = (ks + 1) & 1;
      __syncthreads();
      *(uint4*)&As[nb][ra * 40 + ka] = na0; *(uint4*)&As[nb][ra * 40 + ka + 8] = na1;
      *(uint4*)&Bs[nb][ra * 40 + ka] = nb0; *(uint4*)&Bs[nb][ra * 40 + ka + 8] = nb1;
    }
  }
  #pragma unroll
  for (int n = 0; n < 4; ++n) {
    int gcol = bn + wc * 64 + n * 16 + (lane & 15);
    if (gcol >= 2016) continue;
    float bias = bias_a[gcol];
    #pragma unroll
    for (int m = 0; m < 4; ++m) {
      int grow0 = bm + wr * 64 + m * 16 + (lane >> 4) * 4;
      #pragma unroll
      for (int r = 0; r < 4; ++r) {
        float v = acc[m][n][r] + bias;
        Cf32[(size_t)(grow0 + r) * 2016 + gcol] = 1.f / (1.f + expf(-v));
      }
    }
  }
}

// ---------------- host launch ----------------
extern "C" void kernel_launch(void* const* d_in, const int* in_sizes, int n_in,
                              void* d_out, int out_size, void* d_ws, size_t ws_size,
                              hipStream_t stream) {
  const float* x   = (const float*)d_in[0];
  const int*   ei  = (const int*)d_in[1];
  const float* eps = (const float*)d_in[3];
  const float* W1  = (const float*)d_in[4];  const float* b1  = (const float*)d_in[5];
  const float* W2  = (const float*)d_in[6];  const float* b2  = (const float*)d_in[7];
  const float* W3  = (const float*)d_in[8];  const float* b3  = (const float*)d_in[9];
  const float* Wf1 = (const float*)d_in[10]; const float* bf1 = (const float*)d_in[11];
  const float* Wf2 = (const float*)d_in[12]; const float* bf2v= (const float*)d_in[13];
  float* dout = (float*)d_out;
  char* ws = (char*)d_ws;

  // workspace: 6,422,528 bytes
  u16* Ah2  = (u16*)(ws + 0);         // 4,194,304  [512][64][64] f16 = 2*Lhat
  u16* W1p  = (u16*)(ws + 4194304);   //   458,752  fragment-packed W1
  u16* W23p = (u16*)(ws + 4653056);   //   458,752  fragment-packed [W2|W3]
  u16* Wf2t = (u16*)(ws + 5111808);   // 1,048,576  [2048][256]
  u16* hh   = (u16*)(ws + 6160384);   //   262,144  [512][256]

  k_prep<<<dim3(224), dim3(256), 0, stream>>>(W1, W2, W3, W1p, W23p);
  k_tr<256, 2016><<<dim3(4, 32), dim3(256), 0, stream>>>(Wf2, Wf2t);
  k_buildA<<<dim3(NGR), dim3(256), 0, stream>>>(ei, Ah2);
  k_main  <<<dim3(NGR), dim3(512), 81152, stream>>>(Ah2, x, W1p, b1, W23p, b2, b3,
                                                    eps, Wf1, bf1, dout, hh);
  k_gemm_sig<<<dim3(4, 16), dim3(256), 0, stream>>>(hh, Wf2t, bf2v, dout);
}

// Round 32
// 125.659 us; speedup vs baseline: 1.4210x; 1.4210x over previous
//
#include <hip/hip_runtime.h>

typedef unsigned int uint;
typedef unsigned short u16;
typedef _Float16 f16;
typedef __attribute__((ext_vector_type(8))) _Float16 f16x8;
typedef __attribute__((ext_vector_type(4))) float f32x4;

#define NGR 512
#define EDG 1048576

union uhcv { u16 u; f16 h; };
__device__ __forceinline__ u16 f2h(float f) { uhcv x; x.h = (f16)f; return x.u; }
__device__ __forceinline__ float h2f(u16 v) { uhcv x; x.u = v; return (float)x.h; }

// ---------------- fragment-pack weights f32 -> f16 ----------------
// W1p  layout [kk(7)][ks(4)][nt(16)][G(4)][l15(16)][8]  : frag (k,ks,ntile) is 1024 contiguous bytes
// W23p layout [kk(7)][ks(8)][nt(8)] [G(4)][l15(16)][8]
__global__ __launch_bounds__(256) void k_prep(const float* __restrict__ W1, const float* __restrict__ W2,
                                              const float* __restrict__ W3,
                                              u16* __restrict__ W1p, u16* __restrict__ W23p) {
  int b = blockIdx.x, t = threadIdx.x;
  if (b < 112) {                    // W1p: 28672 groups of 8
    int g = b * 256 + t;
    int l15 = g & 15, G = (g >> 4) & 3, nt = (g >> 6) & 15, ksk = g >> 10;  // ksk = kk*4+ks
    int f0 = ksk * 32 + G * 8;      // = kk*128 + ks*32 + G*8
    int n = nt * 16 + l15;
    u16 out[8];
    #pragma unroll
    for (int j = 0; j < 8; ++j) out[j] = f2h(W1[(size_t)(f0 + j) * 256 + n]);
    *(uint4*)&W1p[(size_t)g * 8] = *(uint4*)out;
  } else {                          // W23p: 28672 groups
    int g = (b - 112) * 256 + t;
    int l15 = g & 15, G = (g >> 4) & 3, nt = (g >> 6) & 7, ksk = g >> 9;    // ksk = kk*8+ks
    int f0 = ksk * 32 + G * 8;      // = kk*256 + ks*32 + G*8
    int n = nt * 16 + l15;
    u16 out[8];
    #pragma unroll
    for (int j = 0; j < 8; ++j) {
      int f = f0 + j;
      float v = (n < 64) ? W2[(size_t)f * 64 + n] : W3[(size_t)f * 64 + (n - 64)];
      out[j] = f2h(v);
    }
    *(uint4*)&W23p[(size_t)g * 8] = *(uint4*)out;
  }
}

// ---------------- coalesced tiled transpose f32 -> f16 (head weight only) ----------------
template<int R, int C>
__global__ __launch_bounds__(256) void k_tr(const float* __restrict__ A, u16* __restrict__ dst) {
  __shared__ u16 tile[64][68];
  int r0 = blockIdx.x * 64, c0 = blockIdx.y * 64;
  int t = threadIdx.x;
  int cl = t & 63, rl = t >> 6;
  #pragma unroll
  for (int pass = 0; pass < 16; ++pass) {
    int r = r0 + rl + pass * 4, c = c0 + cl;
    float v = 0.f;
    if (r < R && c < C) v = A[(size_t)r * C + c];
    tile[cl][rl + pass * 4] = f2h(v);
  }
  __syncthreads();
  int nl = t >> 2, rs = (t & 3) * 16;
  #pragma unroll
  for (int j = 0; j < 4; ++j) {
    uint2 v = *(const uint2*)&tile[nl][rs + j * 4];
    *(uint2*)&dst[(size_t)(c0 + nl) * R + r0 + rs + j * 4] = v;
  }
}

// ---------------- per-graph dense 2*Lhat (f16, [512][64][64]) ----------------
__global__ __launch_bounds__(256) void k_buildA(const int* __restrict__ ei, u16* __restrict__ Ah2) {
  int g = blockIdx.x, t = threadIdx.x;
  __shared__ float sA[64 * 66];
  __shared__ int ideg[64];
  __shared__ float sdis[64];
  for (int e = t; e < 64 * 66; e += 256) sA[e] = 0.f;
  if (t < 64) ideg[t] = 0;
  __syncthreads();
  int sl[4], dl[4];
  #pragma unroll
  for (int u = 0; u < 4; ++u) {
    int idx = g * 1024 + t + u * 256;
    sl[u] = ei[idx] & 63; dl[u] = ei[EDG + idx] & 63;
    atomicAdd(&ideg[sl[u]], 1); atomicAdd(&ideg[dl[u]], 1);
  }
  __syncthreads();
  if (t < 64) sdis[t] = rsqrtf((float)ideg[t]);
  __syncthreads();
  #pragma unroll
  for (int u = 0; u < 4; ++u) {
    float wg = -sdis[sl[u]] * sdis[dl[u]];
    atomicAdd(&sA[sl[u] * 66 + dl[u]], wg);
    atomicAdd(&sA[dl[u] * 66 + sl[u]], wg);
  }
  __syncthreads();
  for (int e = t; e < 4096; e += 256)
    Ah2[(size_t)g * 4096 + e] = f2h(2.f * sA[(e >> 6) * 66 + (e & 63)]);
}

// ======== fused main: both Cheb stages per graph, h1 stays in LDS; pool+reparam+MLP1 tail ========
// LDS: Ah[64][72] @0 | cur[64][264] @9216 (node-major) | curT[256][72] @43008 (feat-major)
//      smu2[256] @79872 (1KB) | sz[64] @80896 | total 81152 -> 2 blocks/CU
__global__ __launch_bounds__(512, 4) void k_main(
    const u16* __restrict__ Ah2, const float* __restrict__ x,
    const u16* __restrict__ W1p, const float* __restrict__ b1,
    const u16* __restrict__ W23p, const float* __restrict__ b2, const float* __restrict__ b3,
    const float* __restrict__ eps, const float* __restrict__ Wf1, const float* __restrict__ bf1,
    float* __restrict__ dout, u16* __restrict__ hh) {
  extern __shared__ char smem[];
  u16* Ah     = (u16*)(smem);
  u16* cur    = (u16*)(smem + 9216);
  u16* curT   = (u16*)(smem + 43008);
  float* smu2 = (float*)(smem + 79872);
  float* sz   = (float*)(smem + 80896);
  int g = blockIdx.x, t = threadIdx.x;
  int lane = t & 63, w = t >> 6, l15 = lane & 15, G = lane >> 4;
  int G16l = G * 16 + l15;                     // fragment lane slot (0..63)
  int mg = w >> 2, ng = w & 3;                 // phase-2 consumption split: 2 m-groups x 4 n-groups

  // stage 2*Lhat (512 uint4 = one pass of 512 threads) and T0 = x (128 feats)
  {
    const uint4* src = (const uint4*)(Ah2 + (size_t)g * 4096);
    {
      int p = t;
      int r = p >> 3, c8 = (p & 7) * 8;
      *(uint4*)&Ah[r * 72 + c8] = src[p];
    }
    const float4* xg = (const float4*)(x + (size_t)g * 8192);
    #pragma unroll
    for (int i = 0; i < 4; ++i) {
      int p = t + i * 512;
      int r = p >> 5, c4 = (p & 31) * 4;
      float4 v = xg[p];
      u16 e0 = f2h(v.x), e1 = f2h(v.y), e2 = f2h(v.z), e3 = f2h(v.w);
      uint2 pk; u16* ps = (u16*)&pk; ps[0] = e0; ps[1] = e1; ps[2] = e2; ps[3] = e3;
      *(uint2*)&cur[r * 264 + c4] = pk;
      curT[(c4 + 0) * 72 + r] = e0; curT[(c4 + 1) * 72 + r] = e1;
      curT[(c4 + 2) * 72 + r] = e2; curT[(c4 + 3) * 72 + r] = e3;
    }
  }
  __syncthreads();

  // ===== phase 1: h1 = relu(sum_k T_k @ W1[k] + b1) =====
  f32x4 accA[4][2];
  #pragma unroll
  for (int m = 0; m < 4; ++m) { accA[m][0] = (f32x4){0,0,0,0}; accA[m][1] = (f32x4){0,0,0,0}; }
  uint2 pA[4], pB[4];
  #pragma unroll
  for (int m = 0; m < 4; ++m) {
    pA[m] = *(const uint2*)&curT[(w * 16 + l15) * 72 + m * 16 + G * 4];
    pB[m] = pA[m];
  }

  for (int k = 1; k <= 7; ++k) {
    // consume T_{k-1} with W1[k-1]: fragment-packed, fully-coalesced 1KB wave loads
    #pragma unroll
    for (int ks = 0; ks < 4; ++ks) {
      f16x8 bb0 = *(const f16x8*)(W1p + (size_t)((((k - 1) * 4 + ks) * 16 + (w * 2 + 0)) * 64 + G16l) * 8);
      f16x8 bb1 = *(const f16x8*)(W1p + (size_t)((((k - 1) * 4 + ks) * 16 + (w * 2 + 1)) * 64 + G16l) * 8);
      #pragma unroll
      for (int m = 0; m < 4; ++m) {
        f16x8 a4 = *(const f16x8*)&cur[(m * 16 + l15) * 264 + ks * 32 + G * 8];
        accA[m][0] = __builtin_amdgcn_mfma_f32_16x16x32_f16(a4, bb0, accA[m][0], 0, 0, 0);
        accA[m][1] = __builtin_amdgcn_mfma_f32_16x16x32_f16(a4, bb1, accA[m][1], 0, 0, 0);
      }
    }
    if (k == 7) break;
    // T_k = (2L)@T_{k-1} - T_{k-2}: seed acc with -T_{k-2}; k==1 -> seed 0, scale 0.5
    f32x4 accY[4];
    #pragma unroll
    for (int m = 0; m < 4; ++m) {
      const u16* pp = (const u16*)&pB[m];
      #pragma unroll
      for (int r = 0; r < 4; ++r) accY[m][r] = (k >= 2) ? -h2f(pp[r]) : 0.f;
    }
    #pragma unroll
    for (int ks = 0; ks < 2; ++ks) {
      f16x8 bq = *(const f16x8*)&curT[(w * 16 + l15) * 72 + ks * 32 + G * 8];
      #pragma unroll
      for (int m = 0; m < 4; ++m) {
        f16x8 a = *(const f16x8*)&Ah[(m * 16 + l15) * 72 + ks * 32 + G * 8];
        accY[m] = __builtin_amdgcn_mfma_f32_16x16x32_f16(a, bq, accY[m], 0, 0, 0);
      }
    }
    __syncthreads();
    {
      int f = w * 16 + l15;
      float sc = (k == 1) ? 0.5f : 1.f;
      #pragma unroll
      for (int m = 0; m < 4; ++m) {
        int i0 = m * 16 + G * 4;
        uint2 pk; u16* ps = (u16*)&pk;
        #pragma unroll
        for (int r = 0; r < 4; ++r) ps[r] = f2h(sc * accY[m][r]);
        *(uint2*)&curT[f * 72 + i0] = pk;
        cur[(i0 + 0) * 264 + f] = ps[0]; cur[(i0 + 1) * 264 + f] = ps[1];
        cur[(i0 + 2) * 264 + f] = ps[2]; cur[(i0 + 3) * 264 + f] = ps[3];
        pB[m] = pA[m]; pA[m] = pk;
      }
    }
    __syncthreads();
  }
  __syncthreads();   // cons(T6) reads complete before h1 overwrites LDS

  // h1 epilogue -> phase-2 T0 (LDS + packed frags; phase-2 recurrence ownership == phase-1 output cols)
  uint2 pA2[4][2], pB2[4][2];
  #pragma unroll
  for (int nc = 0; nc < 2; ++nc) {
    int gc = w * 32 + nc * 16 + l15;
    float bias = b1[gc];
    #pragma unroll
    for (int m = 0; m < 4; ++m) {
      int i0 = m * 16 + G * 4;
      uint2 pk; u16* ps = (u16*)&pk;
      #pragma unroll
      for (int r = 0; r < 4; ++r) {
        float v = accA[m][nc][r] + bias;
        ps[r] = f2h(v > 0.f ? v : 0.f);
      }
      *(uint2*)&curT[gc * 72 + i0] = pk;
      cur[(i0 + 0) * 264 + gc] = ps[0]; cur[(i0 + 1) * 264 + gc] = ps[1];
      cur[(i0 + 2) * 264 + gc] = ps[2]; cur[(i0 + 3) * 264 + gc] = ps[3];
      pA2[m][nc] = pk; pB2[m][nc] = pk;
    }
  }
  __syncthreads();

  // ===== phase 2: out2 = sum_k T_k @ [W2|W3][k], T over h1 (256 feats) =====
  // consumption m-split: wave (mg,ng) owns m-tiles {mg*2, mg*2+1} x col-tiles {ng*2, ng*2+1}
  f32x4 accB[2][2];
  #pragma unroll
  for (int mm = 0; mm < 2; ++mm) { accB[mm][0] = (f32x4){0,0,0,0}; accB[mm][1] = (f32x4){0,0,0,0}; }
  for (int k = 1; k <= 7; ++k) {
    #pragma unroll
    for (int ks = 0; ks < 8; ++ks) {
      f16x8 bb0 = *(const f16x8*)(W23p + (size_t)((((k - 1) * 8 + ks) * 8 + (ng * 2 + 0)) * 64 + G16l) * 8);
      f16x8 bb1 = *(const f16x8*)(W23p + (size_t)((((k - 1) * 8 + ks) * 8 + (ng * 2 + 1)) * 64 + G16l) * 8);
      #pragma unroll
      for (int mm = 0; mm < 2; ++mm) {
        f16x8 a4 = *(const f16x8*)&cur[((mg * 2 + mm) * 16 + l15) * 264 + ks * 32 + G * 8];
        accB[mm][0] = __builtin_amdgcn_mfma_f32_16x16x32_f16(a4, bb0, accB[mm][0], 0, 0, 0);
        accB[mm][1] = __builtin_amdgcn_mfma_f32_16x16x32_f16(a4, bb1, accB[mm][1], 0, 0, 0);
      }
    }
    if (k == 7) break;
    f32x4 accY[4][2];
    #pragma unroll
    for (int m = 0; m < 4; ++m)
      #pragma unroll
      for (int nt = 0; nt < 2; ++nt) {
        const u16* pp = (const u16*)&pB2[m][nt];
        #pragma unroll
        for (int r = 0; r < 4; ++r) accY[m][nt][r] = (k >= 2) ? -h2f(pp[r]) : 0.f;
      }
    #pragma unroll
    for (int ks = 0; ks < 2; ++ks) {
      f16x8 bq0 = *(const f16x8*)&curT[(w * 32 + l15) * 72 + ks * 32 + G * 8];
      f16x8 bq1 = *(const f16x8*)&curT[(w * 32 + 16 + l15) * 72 + ks * 32 + G * 8];
      #pragma unroll
      for (int m = 0; m < 4; ++m) {
        f16x8 a = *(const f16x8*)&Ah[(m * 16 + l15) * 72 + ks * 32 + G * 8];
        accY[m][0] = __builtin_amdgcn_mfma_f32_16x16x32_f16(a, bq0, accY[m][0], 0, 0, 0);
        accY[m][1] = __builtin_amdgcn_mfma_f32_16x16x32_f16(a, bq1, accY[m][1], 0, 0, 0);
      }
    }
    __syncthreads();
    {
      float sc = (k == 1) ? 0.5f : 1.f;
      #pragma unroll
      for (int nt = 0; nt < 2; ++nt) {
        int f = w * 32 + nt * 16 + l15;
        #pragma unroll
        for (int m = 0; m < 4; ++m) {
          int i0 = m * 16 + G * 4;
          uint2 pk; u16* ps = (u16*)&pk;
          #pragma unroll
          for (int r = 0; r < 4; ++r) ps[r] = f2h(sc * accY[m][nt][r]);
          *(uint2*)&curT[f * 72 + i0] = pk;
          cur[(i0 + 0) * 264 + f] = ps[0]; cur[(i0 + 1) * 264 + f] = ps[1];
          cur[(i0 + 2) * 264 + f] = ps[2]; cur[(i0 + 3) * 264 + f] = ps[3];
          pB2[m][nt] = pA2[m][nt]; pA2[m][nt] = pk;
        }
      }
    }
    __syncthreads();
  }
  // ---- pool over 64 nodes (2-partial: mg halves) + reparameterize + MLP1 ----
  #pragma unroll
  for (int nc = 0; nc < 2; ++nc) {
    float s = 0.f;
    #pragma unroll
    for (int mm = 0; mm < 2; ++mm)
      #pragma unroll
      for (int r = 0; r < 4; ++r) s += accB[mm][nc][r];
    s += __shfl_xor(s, 16);
    s += __shfl_xor(s, 32);
    if (G == 0) smu2[mg * 128 + ng * 32 + nc * 16 + l15] = s;
  }
  __syncthreads();
  if (t < 64) {
    float m = (smu2[t] + smu2[128 + t]) * (1.f / 64.f) + b2[t];
    float l = (smu2[64 + t] + smu2[192 + t]) * (1.f / 64.f) + b3[t];
    float z = m + eps[g * 64 + t] * expf(0.5f * l);
    dout[1032192 + g * 64 + t] = m;
    dout[1032192 + 32768 + g * 64 + t] = l;
    sz[t] = z;
  }
  __syncthreads();
  if (t < 256) {
    float aq = bf1[t];
    #pragma unroll 8
    for (int j = 0; j < 64; ++j) aq += sz[j] * Wf1[j * 256 + t];
    hh[(size_t)g * 256 + t] = f2h(aq > 0.f ? aq : 0.f);
  }
}

// ---------------- sigmoid GEMM: adj = sigmoid(hh[512][256] @ Wf2t^T + bf2) ----------------
__global__ __launch_bounds__(256) void k_gemm_sig(const u16* __restrict__ A,
                                                  const u16* __restrict__ Bt,
                                                  const float* __restrict__ bias_a,
                                                  float* __restrict__ Cf32) {
  __shared__ __align__(16) u16 As[2][128 * 40];
  __shared__ __align__(16) u16 Bs[2][128 * 40];
  int t = threadIdx.x;
  int lane = t & 63, wave = t >> 6;
  int wr = wave >> 1, wc = wave & 1;
  int bm = blockIdx.x * 128, bn = blockIdx.y * 128;
  int ra = t >> 1, ka = (t & 1) * 16;
  const u16* Ap = A + (size_t)(bm + ra) * 256 + ka;
  const u16* Bp = Bt + (size_t)(bn + ra) * 256 + ka;

  f32x4 acc[4][4];
  #pragma unroll
  for (int m = 0; m < 4; ++m)
    #pragma unroll
    for (int n = 0; n < 4; ++n) acc[m][n] = (f32x4){0.f, 0.f, 0.f, 0.f};

  {
    uint4 a0 = *(const uint4*)(Ap), a1 = *(const uint4*)(Ap + 8);
    uint4 b0 = *(const uint4*)(Bp), b1 = *(const uint4*)(Bp + 8);
    *(uint4*)&As[0][ra * 40 + ka] = a0; *(uint4*)&As[0][ra * 40 + ka + 8] = a1;
    *(uint4*)&Bs[0][ra * 40 + ka] = b0; *(uint4*)&Bs[0][ra * 40 + ka + 8] = b1;
  }
  for (int ks = 0; ks < 8; ++ks) {
    int cu = ks & 1;
    uint4 na0, na1, nb0, nb1;
    bool pf = (ks + 1 < 8);
    if (pf) {
      int k0 = (ks + 1) << 5;
      na0 = *(const uint4*)(Ap + k0); na1 = *(const uint4*)(Ap + k0 + 8);
      nb0 = *(const uint4*)(Bp + k0); nb1 = *(const uint4*)(Bp + k0 + 8);
    }
    __syncthreads();
    f16x8 af[4], bfr[4];
    #pragma unroll
    for (int m = 0; m < 4; ++m)
      af[m] = *(const f16x8*)&As[cu][(wr * 64 + m * 16 + (lane & 15)) * 40 + (lane >> 4) * 8];
    #pragma unroll
    for (int n = 0; n < 4; ++n)
      bfr[n] = *(const f16x8*)&Bs[cu][(wc * 64 + n * 16 + (lane & 15)) * 40 + (lane >> 4) * 8];
    #pragma unroll
    for (int m = 0; m < 4; ++m)
      #pragma unroll
      for (int n = 0; n < 4; ++n)
        acc[m][n] = __builtin_amdgcn_mfma_f32_16x16x32_f16(af[m], bfr[n], acc[m][n], 0, 0, 0);
    if (pf) {
      int nb = (ks + 1) & 1;
      __syncthreads();
      *(uint4*)&As[nb][ra * 40 + ka] = na0; *(uint4*)&As[nb][ra * 40 + ka + 8] = na1;
      *(uint4*)&Bs[nb][ra * 40 + ka] = nb0; *(uint4*)&Bs[nb][ra * 40 + ka + 8] = nb1;
    }
  }
  #pragma unroll
  for (int n = 0; n < 4; ++n) {
    int gcol = bn + wc * 64 + n * 16 + (lane & 15);
    if (gcol >= 2016) continue;
    float bias = bias_a[gcol];
    #pragma unroll
    for (int m = 0; m < 4; ++m) {
      int grow0 = bm + wr * 64 + m * 16 + (lane >> 4) * 4;
      #pragma unroll
      for (int r = 0; r < 4; ++r) {
        float v = acc[m][n][r] + bias;
        Cf32[(size_t)(grow0 + r) * 2016 + gcol] = 1.f / (1.f + expf(-v));
      }
    }
  }
}

// ---------------- host launch ----------------
extern "C" void kernel_launch(void* const* d_in, const int* in_sizes, int n_in,
                              void* d_out, int out_size, void* d_ws, size_t ws_size,
                              hipStream_t stream) {
  const float* x   = (const float*)d_in[0];
  const int*   ei  = (const int*)d_in[1];
  const float* eps = (const float*)d_in[3];
  const float* W1  = (const float*)d_in[4];  const float* b1  = (const float*)d_in[5];
  const float* W2  = (const float*)d_in[6];  const float* b2  = (const float*)d_in[7];
  const float* W3  = (const float*)d_in[8];  const float* b3  = (const float*)d_in[9];
  const float* Wf1 = (const float*)d_in[10]; const float* bf1 = (const float*)d_in[11];
  const float* Wf2 = (const float*)d_in[12]; const float* bf2v= (const float*)d_in[13];
  float* dout = (float*)d_out;
  char* ws = (char*)d_ws;

  // workspace: 6,422,528 bytes
  u16* Ah2  = (u16*)(ws + 0);         // 4,194,304  [512][64][64] f16 = 2*Lhat
  u16* W1p  = (u16*)(ws + 4194304);   //   458,752  fragment-packed W1
  u16* W23p = (u16*)(ws + 4653056);   //   458,752  fragment-packed [W2|W3]
  u16* Wf2t = (u16*)(ws + 5111808);   // 1,048,576  [2048][256]
  u16* hh   = (u16*)(ws + 6160384);   //   262,144  [512][256]

  k_prep<<<dim3(224), dim3(256), 0, stream>>>(W1, W2, W3, W1p, W23p);
  k_tr<256, 2016><<<dim3(4, 32), dim3(256), 0, stream>>>(Wf2, Wf2t);
  k_buildA<<<dim3(NGR), dim3(256), 0, stream>>>(ei, Ah2);
  k_main  <<<dim3(NGR), dim3(512), 81152, stream>>>(Ah2, x, W1p, b1, W23p, b2, b3,
                                                    eps, Wf1, bf1, dout, hh);
  k_gemm_sig<<<dim3(4, 16), dim3(256), 0, stream>>>(hh, Wf2t, bf2v, dout);
}